// Round 1
// baseline (7324.681 us; speedup 1.0000x reference)
//
#include <hip/hip_runtime.h>
#include <math.h>

constexpr int SEQ_L = 2048;
constexpr int EDIM  = 300;
constexpr int NCLS  = 20;
constexpr unsigned SENT = 0xFFA5A5A5u;  // NaN payload: unproducible by finite math
constexpr int NWG = 128;                // oversubscribed candidate WGs for rnn

typedef float f32x4 __attribute__((ext_vector_type(4)));

// ---------------------------------------------------------------------------
// init: Hbuf[0] = h_0 = zeros; Hbuf[1..2048] = sentinel; census area zeroed.
// Hbuf = 2049*1024 f32 = 524544 uint4; census = 256 dwords = 64 uint4 after it.
// Census MUST be re-zeroed every graph replay (init runs before rnn on stream).
// ---------------------------------------------------------------------------
__global__ __launch_bounds__(256) void init_kernel(uint4* H) {
  const int NT = 513 * 256;
  int idx = blockIdx.x * blockDim.x + threadIdx.x;
  const uint4 z = {0u, 0u, 0u, 0u};
  const uint4 s = {SENT, SENT, SENT, SENT};
#pragma unroll
  for (int i = 0; i < 4; ++i) {
    int q = i * NT + idx;
    if (q < 524608) H[q] = (q < 256 || q >= 524544) ? z : s;
  }
}

// ---------------------------------------------------------------------------
// gi = x @ Wih^T + bih (+ bhh folded for r,z). grid (SEQ_L/8, 2), block 256.
// ---------------------------------------------------------------------------
__global__ __launch_bounds__(256) void gi_kernel(
    const int* __restrict__ seq, const float* __restrict__ emb,
    const float* __restrict__ Wih_f, const float* __restrict__ bih_f,
    const float* __restrict__ bhh_f,
    const float* __restrict__ Wih_b, const float* __restrict__ bih_b,
    const float* __restrict__ bhh_b,
    float* __restrict__ gi_f, float* __restrict__ gi_b) {
  const int d = blockIdx.y;
  const float* Wih = d ? Wih_b : Wih_f;
  const float* bih = d ? bih_b : bih_f;
  const float* bhh = d ? bhh_b : bhh_f;
  float* gi = d ? gi_b : gi_f;
  const int t0 = blockIdx.x * 8;
  const int tid = threadIdx.x;

  __shared__ float xs[8][304];

  for (int i = tid; i < 8 * 75; i += 256) {
    int tt = i / 75, u = i - tt * 75;
    int t = t0 + tt;
    int s = seq[d ? (SEQ_L - 1 - t) : t];
    const float4* p = reinterpret_cast<const float4*>(emb + (size_t)s * EDIM);
    float4 v = p[u];
    xs[tt][u * 4 + 0] = v.x; xs[tt][u * 4 + 1] = v.y;
    xs[tt][u * 4 + 2] = v.z; xs[tt][u * 4 + 3] = v.w;
  }
  __syncthreads();

  for (int rr = 0; rr < 6; ++rr) {
    int j = rr * 256 + tid;
    const float4* wrow = reinterpret_cast<const float4*>(Wih + (size_t)j * EDIM);
    float acc[8];
#pragma unroll
    for (int tt = 0; tt < 8; ++tt) acc[tt] = 0.0f;
    for (int q = 0; q < EDIM / 4; ++q) {
      float4 w = wrow[q];
#pragma unroll
      for (int tt = 0; tt < 8; ++tt)
        acc[tt] += w.x * xs[tt][4 * q] + w.y * xs[tt][4 * q + 1] +
                   w.z * xs[tt][4 * q + 2] + w.w * xs[tt][4 * q + 3];
    }
    float bb = bih[j] + (j < 1024 ? bhh[j] : 0.0f);
#pragma unroll
    for (int tt = 0; tt < 8; ++tt)
      gi[(size_t)(t0 + tt) * 1536 + j] = acc[tt] + bb;
  }
}

// ---------------------------------------------------------------------------
// Recurrence. 128 candidate WGs x 512 thr; census (HW_REG_XCC_ID) elects
// 16 WGs per direction consolidated on ONE XCD each (pigeonhole: max-count
// XCD always has >=16 of 128). Fast path exchanges h through the local L2:
// producers dual-store (plain -> local L2, agent -> IC); consumers poll with
// sc0 loads (L1-bypass, L2-hit), bounded + strike counter -> permanent
// agent-scope fallback, so every placement/flag assumption is hang-proof.
// Per-wave gates: wave w's 12 Whh rows are exactly r/z/n of its own 4
// outputs -> one __syncthreads per step (hsh double-buffered), no wave-0
// serialization. All fp expression orders identical to baseline (bit-exact).
// ---------------------------------------------------------------------------
__global__ __launch_bounds__(512, 2) void rnn_kernel(
    const float* __restrict__ Whh_f, const float* __restrict__ bhh_f,
    const float* __restrict__ Whh_b, const float* __restrict__ bhh_b,
    const float* __restrict__ gi_f, const float* __restrict__ gi_b,
    float* Hbuf, unsigned* census) {
  const int tid  = threadIdx.x;
  const int lane = tid & 63;
  const int w    = tid >> 6;
  const int bid  = blockIdx.x;

  __shared__ int cen[NWG];
  __shared__ int s_dir, s_slot, s_fast;

  // --- census publish (thread 0) ---
  if (tid == 0) {
    unsigned xcd;
    asm volatile("s_getreg_b32 %0, hwreg(HW_REG_XCC_ID, 0, 32)" : "=s"(xcd));
    __hip_atomic_store(&census[bid], (xcd & 7u) + 1u, __ATOMIC_RELAXED,
                       __HIP_MEMORY_SCOPE_AGENT);
  }
  // --- gather: all 128 WGs are co-resident (<=1 WG/CU worst case), so
  // per-entry spins always terminate ---
  if (tid < NWG) {
    unsigned v;
    do {
      v = __hip_atomic_load(&census[tid], __ATOMIC_RELAXED,
                            __HIP_MEMORY_SCOPE_AGENT);
    } while (v == 0u);
    cen[tid] = (int)v - 1;
  }
  __syncthreads();

  // --- deterministic role assignment (every WG computes the same) ---
  if (tid == 0) {
    int counts[8] = {0, 0, 0, 0, 0, 0, 0, 0};
    for (int i = 0; i < NWG; ++i) counts[cen[i]]++;
    int x0 = 0;
    for (int x = 1; x < 8; ++x) if (counts[x] > counts[x0]) x0 = x;
    int x1, local1;
    if (counts[x0] >= 32) { x1 = x0; local1 = 1; }
    else {
      int best = -1;
      for (int x = 0; x < 8; ++x)
        if (x != x0 && (best < 0 || counts[x] > counts[best])) best = x;
      if (counts[best] >= 16) { x1 = best; local1 = 1; }
      else { x1 = -1; local1 = 0; }
    }
    int myx = cen[bid];
    int rankx = 0;
    for (int i = 0; i < bid; ++i) if (cen[i] == myx) rankx++;
    int dir = -1, slot = 0, fast = 0;
    if (myx == x0 && rankx < 16) { dir = 0; slot = rankx; fast = 1; }
    else if (local1 && x1 == x0 && myx == x0 && rankx >= 16 && rankx < 32) {
      dir = 1; slot = rankx - 16; fast = 1;
    } else if (local1 && x1 != x0 && myx == x1 && rankx < 16) {
      dir = 1; slot = rankx; fast = 1;
    } else if (!local1) {
      // scattered dir1: first 16 blocks that are not dir0 workers
      int cx0 = 0, k = 0, rs = -1;
      for (int i = 0; i < NWG; ++i) {
        bool isd0 = (cen[i] == x0) && (cx0 < 16);
        if (cen[i] == x0) cx0++;
        if (!isd0) { if (i == bid) rs = k; k++; }
      }
      if (rs >= 0 && rs < 16) { dir = 1; slot = rs; fast = 0; }
    }
    s_dir = dir; s_slot = slot; s_fast = fast;
  }
  __syncthreads();
  const int dir = s_dir, fast = s_fast;
  if (dir < 0) return;  // non-worker
  const int j0 = s_slot * 32;

  const float* Whh = dir ? Whh_b : Whh_f;
  const float* bhh = dir ? bhh_b : bhh_f;
  const float* gi  = dir ? gi_b : gi_f;

  alignas(16) __shared__ float hsh[2][512];   // double-buffered by t&1
  alignas(16) __shared__ float part[8][12][68];

  // wave w, row r = g*4+jj -> Whh row g*512 + j0 + w*4 + jj; lane cols *8..+7
  f32x4 Wv[24];
#pragma unroll
  for (int g = 0; g < 3; ++g)
#pragma unroll
    for (int jj = 0; jj < 4; ++jj) {
      const f32x4* rp = reinterpret_cast<const f32x4*>(
                            Whh + (size_t)(g * 512 + j0 + w * 4 + jj) * 512) +
                        lane * 2;
      Wv[(g * 4 + jj) * 2]     = rp[0];
      Wv[(g * 4 + jj) * 2 + 1] = rp[1];
    }

  float bhn = 0.0f;
  if (lane < 4) bhn = bhh[1024 + j0 + w * 4 + lane];
  float hprev = 0.0f;  // lane jj<4 carries h for output j0+w*4+jj
  int strikes = 0;

  for (int t = 0; t < SEQ_L; ++t) {
    // gi prefetch: lane r=g*4+jj (r<12) loads gi[g*512 + j0 + w*4 + jj];
    // independent of h, hides under the poll.
    float giv = 0.0f;
    if (lane < 12)
      giv = gi[(size_t)t * 1536 + (lane >> 2) * 512 + j0 + w * 4 + (lane & 3)];

    // poll own 64-float slice of h_t (each dword is its own validity flag)
    const float* hp = Hbuf + (size_t)t * 1024 + dir * 512 + w * 64 + lane;
    float hv = 0.0f;
    bool got = false;
    if (fast && strikes < 16) {
      // L2-scope poll: sc0 = bypass L1, served by the (shared, same-XCD) L2.
      for (int it = 0; it < 64 && !got; ++it) {
        unsigned u;
        asm volatile("global_load_dword %0, %1, off sc0\n\ts_waitcnt vmcnt(0)"
                     : "=v"(u) : "v"(hp) : "memory");
        if (__ballot(u == SENT) == 0ull) { hv = __uint_as_float(u); got = true; }
      }
      if (!got) ++strikes;  // too many misses -> distrust fast path
    }
    if (!got) {
      // proven agent-scope poll (always terminates: producers agent-store too)
      for (;;) {
        float x = __hip_atomic_load(hp, __ATOMIC_RELAXED,
                                    __HIP_MEMORY_SCOPE_AGENT);
        if (__ballot(__float_as_uint(x) == SENT) == 0ull) { hv = x; break; }
      }
    }
    hsh[t & 1][w * 64 + lane] = hv;
    __syncthreads();  // the ONLY barrier per step (hsh is double-buffered)

    const f32x4* hq = reinterpret_cast<const f32x4*>(&hsh[t & 1][lane * 8]);
    f32x4 h0 = hq[0], h1 = hq[1];

    float s_[12];
#pragma unroll
    for (int r = 0; r < 12; ++r) {
      f32x4 w0 = Wv[2 * r], w1 = Wv[2 * r + 1];
      s_[r] = w0.x * h0.x + w0.y * h0.y + w0.z * h0.z + w0.w * h0.w +
              w1.x * h1.x + w1.y * h1.y + w1.z * h1.z + w1.w * h1.w;
    }

    // intra-wave LDS transpose-reduce (identical order to baseline)
#pragma unroll
    for (int r = 0; r < 12; ++r) part[w][r][lane] = s_[r];
    __builtin_amdgcn_wave_barrier();
    float red = 0.0f;
    if (lane < 12) {
      const f32x4* rowp = reinterpret_cast<const f32x4*>(&part[w][lane][0]);
      f32x4 a4 = rowp[0];
#pragma unroll
      for (int q = 1; q < 16; ++q) a4 += rowp[q];
      red = (a4.x + a4.y) + (a4.z + a4.w);
    }
    __builtin_amdgcn_wave_barrier();

    // per-wave gates: wave w owns outputs j0+w*4 .. +3
    float redf = red + ((lane < 8) ? giv : 0.0f);  // sr+ir / sz+iz (commutative)
    int qq = lane & 3;
    float v_r = __shfl(redf, qq, 64);
    float v_z = __shfl(redf, 4 + qq, 64);
    float v_n = __shfl(redf, 8 + qq, 64);
    float v_i = __shfl(giv, 8 + qq, 64);
    if (lane < 4) {
      float rr = 1.0f / (1.0f + __expf(-v_r));
      float zz = 1.0f / (1.0f + __expf(-v_z));
      float nn = tanhf(v_i + rr * (v_n + bhn));
      float hnew = (1.0f - zz) * nn + zz * hprev;
      hprev = hnew;
      float* dst = Hbuf + (size_t)(t + 1) * 1024 + dir * 512 + j0 + w * 4 + lane;
      if (fast)  // plain store -> local L2 (write-through L1): fast visibility
        __hip_atomic_store(dst, hnew, __ATOMIC_RELAXED,
                           __HIP_MEMORY_SCOPE_WORKGROUP);
      // agent store -> device coherence point: guarantees the fallback path
      __hip_atomic_store(dst, hnew, __ATOMIC_RELAXED,
                         __HIP_MEMORY_SCOPE_AGENT);
    }
  }
}

// ---------------------------------------------------------------------------
// classifier: hid = relu(W1 @ [hf;hb] + b1); logits = W2 @ hid + b2; softmax
// ---------------------------------------------------------------------------
__global__ __launch_bounds__(1024) void cls_kernel(
    const float* __restrict__ Hfin,  // Hbuf slot SEQ_L: [dir][512]
    const float* __restrict__ W1, const float* __restrict__ b1,
    const float* __restrict__ W2, const float* __restrict__ b2,
    float* __restrict__ out) {
  __shared__ float hcat[1024];
  __shared__ float hid[512];
  __shared__ float logits[NCLS];
  const int tid = threadIdx.x;
  hcat[tid] = Hfin[tid];
  __syncthreads();

  const int lane = tid & 63, widx = tid >> 6;
  for (int rr = 0; rr < 32; ++rr) {
    int row = widx * 32 + rr;
    const float4* wrow = reinterpret_cast<const float4*>(W1 + (size_t)row * 1024);
    float acc = 0.0f;
#pragma unroll
    for (int c = 0; c < 4; ++c) {
      int k = c * 256 + lane * 4;
      float4 v = wrow[c * 64 + lane];
      acc += v.x * hcat[k] + v.y * hcat[k + 1] + v.z * hcat[k + 2] +
             v.w * hcat[k + 3];
    }
#pragma unroll
    for (int mask = 32; mask >= 1; mask >>= 1) acc += __shfl_xor(acc, mask, 64);
    if (lane == 0) hid[row] = fmaxf(acc + b1[row], 0.0f);
  }
  __syncthreads();

  if (tid < NCLS) {
    const float4* wrow = reinterpret_cast<const float4*>(W2 + (size_t)tid * 512);
    float acc = 0.0f;
    for (int q = 0; q < 128; ++q) {
      float4 v = wrow[q];
      int k = q * 4;
      acc += v.x * hid[k] + v.y * hid[k + 1] + v.z * hid[k + 2] +
             v.w * hid[k + 3];
    }
    logits[tid] = acc + b2[tid];
  }
  __syncthreads();

  if (tid == 0) {
    float m = -1e30f;
    for (int i = 0; i < NCLS; ++i) m = fmaxf(m, logits[i]);
    float s = 0.0f;
    float e[NCLS];
    for (int i = 0; i < NCLS; ++i) { e[i] = __expf(logits[i] - m); s += e[i]; }
    float inv = 1.0f / s;
    for (int i = 0; i < NCLS; ++i) out[i] = e[i] * inv;
  }
}

// ---------------------------------------------------------------------------
extern "C" void kernel_launch(void* const* d_in, const int* in_sizes, int n_in,
                              void* d_out, int out_size, void* d_ws,
                              size_t ws_size, hipStream_t stream) {
  (void)in_sizes; (void)n_in; (void)out_size; (void)ws_size;
  const int*   seq   = (const int*)d_in[0];
  const float* emb   = (const float*)d_in[1];
  const float* Wih_f = (const float*)d_in[2];
  const float* Whh_f = (const float*)d_in[3];
  const float* bih_f = (const float*)d_in[4];
  const float* bhh_f = (const float*)d_in[5];
  const float* Wih_b = (const float*)d_in[6];
  const float* Whh_b = (const float*)d_in[7];
  const float* bih_b = (const float*)d_in[8];
  const float* bhh_b = (const float*)d_in[9];
  const float* W1    = (const float*)d_in[10];
  const float* b1    = (const float*)d_in[11];
  const float* W2    = (const float*)d_in[12];
  const float* b2    = (const float*)d_in[13];
  float* out = (float*)d_out;

  float* gi_f = (float*)d_ws;                   // 2048*1536 f32 (12.6 MB)
  float* gi_b = gi_f + (size_t)SEQ_L * 1536;    // 12.6 MB
  float* Hbuf = gi_b + (size_t)SEQ_L * 1536;    // 2049*1024 f32 (8.4 MB)
  unsigned* census = (unsigned*)(Hbuf + (size_t)2049 * 1024);  // 256 dwords

  hipLaunchKernelGGL(init_kernel, dim3(513), dim3(256), 0, stream,
                     (uint4*)Hbuf);
  hipLaunchKernelGGL(gi_kernel, dim3(SEQ_L / 8, 2), dim3(256), 0, stream,
                     seq, emb, Wih_f, bih_f, bhh_f, Wih_b, bih_b, bhh_b,
                     gi_f, gi_b);
  hipLaunchKernelGGL(rnn_kernel, dim3(NWG), dim3(512), 0, stream,
                     Whh_f, bhh_f, Whh_b, bhh_b, gi_f, gi_b, Hbuf, census);
  hipLaunchKernelGGL(cls_kernel, dim3(1), dim3(1024), 0, stream,
                     Hbuf + (size_t)SEQ_L * 1024, W1, b1, W2, b2, out);
}

// Round 2
// 6679.794 us; speedup vs baseline: 1.0965x; 1.0965x over previous
//
#include <hip/hip_runtime.h>
#include <math.h>

constexpr int SEQ_L = 2048;
constexpr int EDIM  = 300;
constexpr int NCLS  = 20;
constexpr unsigned SENT = 0xFFA5A5A5u;  // NaN payload: unproducible by finite math
constexpr int NWG = 128;                // oversubscribed candidate WGs for rnn

typedef float f32x4 __attribute__((ext_vector_type(4)));

// ---------------------------------------------------------------------------
// init: Hbuf[0] = h_0 = zeros; Hbuf[1..2048] = sentinel; census area zeroed.
// Hbuf = 2049*1024 f32 = 524544 uint4; census = 256 dwords = 64 uint4 after it.
// Census MUST be re-zeroed every graph replay (init runs before rnn on stream).
// ---------------------------------------------------------------------------
__global__ __launch_bounds__(256) void init_kernel(uint4* H) {
  const int NT = 513 * 256;
  int idx = blockIdx.x * blockDim.x + threadIdx.x;
  const uint4 z = {0u, 0u, 0u, 0u};
  const uint4 s = {SENT, SENT, SENT, SENT};
#pragma unroll
  for (int i = 0; i < 4; ++i) {
    int q = i * NT + idx;
    if (q < 524608) H[q] = (q < 256 || q >= 524544) ? z : s;
  }
}

// ---------------------------------------------------------------------------
// gi = x @ Wih^T + bih (+ bhh folded for r,z). grid (SEQ_L/8, 2), block 256.
// ---------------------------------------------------------------------------
__global__ __launch_bounds__(256) void gi_kernel(
    const int* __restrict__ seq, const float* __restrict__ emb,
    const float* __restrict__ Wih_f, const float* __restrict__ bih_f,
    const float* __restrict__ bhh_f,
    const float* __restrict__ Wih_b, const float* __restrict__ bih_b,
    const float* __restrict__ bhh_b,
    float* __restrict__ gi_f, float* __restrict__ gi_b) {
  const int d = blockIdx.y;
  const float* Wih = d ? Wih_b : Wih_f;
  const float* bih = d ? bih_b : bih_f;
  const float* bhh = d ? bhh_b : bhh_f;
  float* gi = d ? gi_b : gi_f;
  const int t0 = blockIdx.x * 8;
  const int tid = threadIdx.x;

  __shared__ float xs[8][304];

  for (int i = tid; i < 8 * 75; i += 256) {
    int tt = i / 75, u = i - tt * 75;
    int t = t0 + tt;
    int s = seq[d ? (SEQ_L - 1 - t) : t];
    const float4* p = reinterpret_cast<const float4*>(emb + (size_t)s * EDIM);
    float4 v = p[u];
    xs[tt][u * 4 + 0] = v.x; xs[tt][u * 4 + 1] = v.y;
    xs[tt][u * 4 + 2] = v.z; xs[tt][u * 4 + 3] = v.w;
  }
  __syncthreads();

  for (int rr = 0; rr < 6; ++rr) {
    int j = rr * 256 + tid;
    const float4* wrow = reinterpret_cast<const float4*>(Wih + (size_t)j * EDIM);
    float acc[8];
#pragma unroll
    for (int tt = 0; tt < 8; ++tt) acc[tt] = 0.0f;
    for (int q = 0; q < EDIM / 4; ++q) {
      float4 w = wrow[q];
#pragma unroll
      for (int tt = 0; tt < 8; ++tt)
        acc[tt] += w.x * xs[tt][4 * q] + w.y * xs[tt][4 * q + 1] +
                   w.z * xs[tt][4 * q + 2] + w.w * xs[tt][4 * q + 3];
    }
    float bb = bih[j] + (j < 1024 ? bhh[j] : 0.0f);
#pragma unroll
    for (int tt = 0; tt < 8; ++tt)
      gi[(size_t)(t0 + tt) * 1536 + j] = acc[tt] + bb;
  }
}

// ---------------------------------------------------------------------------
// Recurrence. Same structure as round 1 (census consolidation on one XCD per
// direction; per-wave gates; single barrier/step) with ONE change: the fast
// poll is a workgroup-scope global_atomic_or (RMW executes at the local TCC/
// L2 — architecturally CANNOT be served by a stale L1 line, which is what
// killed the sc0-load poll: FETCH collapsed to streaming-only while dur
// doubled = polls spinning on cached SENT). OR-0 writes back what it read,
// so the write-once-sentinel protocol is preserved; the TCC serializes the
// RMW against the producer's write-through store. Bounded attempts + strike
// counter -> permanent agent-scope fallback keeps every assumption hang-proof.
// ---------------------------------------------------------------------------
__global__ __launch_bounds__(512, 2) void rnn_kernel(
    const float* __restrict__ Whh_f, const float* __restrict__ bhh_f,
    const float* __restrict__ Whh_b, const float* __restrict__ bhh_b,
    const float* __restrict__ gi_f, const float* __restrict__ gi_b,
    float* Hbuf, unsigned* census) {
  const int tid  = threadIdx.x;
  const int lane = tid & 63;
  const int w    = tid >> 6;
  const int bid  = blockIdx.x;

  __shared__ int cen[NWG];
  __shared__ int s_dir, s_slot, s_fast;

  // --- census publish (thread 0) ---
  if (tid == 0) {
    unsigned xcd;
    asm volatile("s_getreg_b32 %0, hwreg(HW_REG_XCC_ID, 0, 32)" : "=s"(xcd));
    __hip_atomic_store(&census[bid], (xcd & 7u) + 1u, __ATOMIC_RELAXED,
                       __HIP_MEMORY_SCOPE_AGENT);
  }
  // --- gather: all 128 WGs are co-resident (<=1 WG/CU worst case), so
  // per-entry spins always terminate ---
  if (tid < NWG) {
    unsigned v;
    do {
      v = __hip_atomic_load(&census[tid], __ATOMIC_RELAXED,
                            __HIP_MEMORY_SCOPE_AGENT);
    } while (v == 0u);
    cen[tid] = (int)v - 1;
  }
  __syncthreads();

  // --- deterministic role assignment (every WG computes the same) ---
  if (tid == 0) {
    int counts[8] = {0, 0, 0, 0, 0, 0, 0, 0};
    for (int i = 0; i < NWG; ++i) counts[cen[i]]++;
    int x0 = 0;
    for (int x = 1; x < 8; ++x) if (counts[x] > counts[x0]) x0 = x;
    int x1, local1;
    if (counts[x0] >= 32) { x1 = x0; local1 = 1; }
    else {
      int best = -1;
      for (int x = 0; x < 8; ++x)
        if (x != x0 && (best < 0 || counts[x] > counts[best])) best = x;
      if (counts[best] >= 16) { x1 = best; local1 = 1; }
      else { x1 = -1; local1 = 0; }
    }
    int myx = cen[bid];
    int rankx = 0;
    for (int i = 0; i < bid; ++i) if (cen[i] == myx) rankx++;
    int dir = -1, slot = 0, fast = 0;
    if (myx == x0 && rankx < 16) { dir = 0; slot = rankx; fast = 1; }
    else if (local1 && x1 == x0 && myx == x0 && rankx >= 16 && rankx < 32) {
      dir = 1; slot = rankx - 16; fast = 1;
    } else if (local1 && x1 != x0 && myx == x1 && rankx < 16) {
      dir = 1; slot = rankx; fast = 1;
    } else if (!local1) {
      // scattered dir1: first 16 blocks that are not dir0 workers
      int cx0 = 0, k = 0, rs = -1;
      for (int i = 0; i < NWG; ++i) {
        bool isd0 = (cen[i] == x0) && (cx0 < 16);
        if (cen[i] == x0) cx0++;
        if (!isd0) { if (i == bid) rs = k; k++; }
      }
      if (rs >= 0 && rs < 16) { dir = 1; slot = rs; fast = 0; }
    }
    s_dir = dir; s_slot = slot; s_fast = fast;
  }
  __syncthreads();
  const int dir = s_dir, fast = s_fast;
  if (dir < 0) return;  // non-worker
  const int j0 = s_slot * 32;

  const float* Whh = dir ? Whh_b : Whh_f;
  const float* bhh = dir ? bhh_b : bhh_f;
  const float* gi  = dir ? gi_b : gi_f;

  alignas(16) __shared__ float hsh[2][512];   // double-buffered by t&1
  alignas(16) __shared__ float part[8][12][68];

  // wave w, row r = g*4+jj -> Whh row g*512 + j0 + w*4 + jj; lane cols *8..+7
  f32x4 Wv[24];
#pragma unroll
  for (int g = 0; g < 3; ++g)
#pragma unroll
    for (int jj = 0; jj < 4; ++jj) {
      const f32x4* rp = reinterpret_cast<const f32x4*>(
                            Whh + (size_t)(g * 512 + j0 + w * 4 + jj) * 512) +
                        lane * 2;
      Wv[(g * 4 + jj) * 2]     = rp[0];
      Wv[(g * 4 + jj) * 2 + 1] = rp[1];
    }

  float bhn = 0.0f;
  if (lane < 4) bhn = bhh[1024 + j0 + w * 4 + lane];
  float hprev = 0.0f;  // lane jj<4 carries h for output j0+w*4+jj
  int strikes = 0;

  for (int t = 0; t < SEQ_L; ++t) {
    // gi prefetch: lane r=g*4+jj (r<12) loads gi[g*512 + j0 + w*4 + jj];
    // independent of h, hides under the poll.
    float giv = 0.0f;
    if (lane < 12)
      giv = gi[(size_t)t * 1536 + (lane >> 2) * 512 + j0 + w * 4 + (lane & 3)];

    // poll own 64-float slice of h_t (each dword is its own validity flag)
    float* hp = Hbuf + (size_t)t * 1024 + dir * 512 + w * 64 + lane;
    float hv = 0.0f;
    bool got = false;
    if (fast && strikes < 16) {
      // L2-scope poll via atomic RMW: executes at the local TCC, so it can
      // never be served by a stale L1 line (the failure mode of sc0 loads).
      unsigned* hpu = reinterpret_cast<unsigned*>(hp);
      for (int it = 0; it < 16 && !got; ++it) {
        unsigned u = __hip_atomic_fetch_or(hpu, 0u, __ATOMIC_RELAXED,
                                           __HIP_MEMORY_SCOPE_WORKGROUP);
        if (__ballot(u == SENT) == 0ull) { hv = __uint_as_float(u); got = true; }
      }
      if (!got) ++strikes;  // fast path not delivering -> distrust it
    }
    if (!got) {
      // proven agent-scope poll (always terminates: producers agent-store too)
      for (;;) {
        float x = __hip_atomic_load(hp, __ATOMIC_RELAXED,
                                    __HIP_MEMORY_SCOPE_AGENT);
        if (__ballot(__float_as_uint(x) == SENT) == 0ull) { hv = x; break; }
      }
    }
    hsh[t & 1][w * 64 + lane] = hv;
    __syncthreads();  // the ONLY barrier per step (hsh is double-buffered)

    const f32x4* hq = reinterpret_cast<const f32x4*>(&hsh[t & 1][lane * 8]);
    f32x4 h0 = hq[0], h1 = hq[1];

    float s_[12];
#pragma unroll
    for (int r = 0; r < 12; ++r) {
      f32x4 w0 = Wv[2 * r], w1 = Wv[2 * r + 1];
      s_[r] = w0.x * h0.x + w0.y * h0.y + w0.z * h0.z + w0.w * h0.w +
              w1.x * h1.x + w1.y * h1.y + w1.z * h1.z + w1.w * h1.w;
    }

    // intra-wave LDS transpose-reduce (identical order to baseline)
#pragma unroll
    for (int r = 0; r < 12; ++r) part[w][r][lane] = s_[r];
    __builtin_amdgcn_wave_barrier();
    float red = 0.0f;
    if (lane < 12) {
      const f32x4* rowp = reinterpret_cast<const f32x4*>(&part[w][lane][0]);
      f32x4 a4 = rowp[0];
#pragma unroll
      for (int q = 1; q < 16; ++q) a4 += rowp[q];
      red = (a4.x + a4.y) + (a4.z + a4.w);
    }
    __builtin_amdgcn_wave_barrier();

    // per-wave gates: wave w owns outputs j0+w*4 .. +3
    float redf = red + ((lane < 8) ? giv : 0.0f);  // sr+ir / sz+iz (commutative)
    int qq = lane & 3;
    float v_r = __shfl(redf, qq, 64);
    float v_z = __shfl(redf, 4 + qq, 64);
    float v_n = __shfl(redf, 8 + qq, 64);
    float v_i = __shfl(giv, 8 + qq, 64);
    if (lane < 4) {
      float rr = 1.0f / (1.0f + __expf(-v_r));
      float zz = 1.0f / (1.0f + __expf(-v_z));
      float nn = tanhf(v_i + rr * (v_n + bhn));
      float hnew = (1.0f - zz) * nn + zz * hprev;
      hprev = hnew;
      float* dst = Hbuf + (size_t)(t + 1) * 1024 + dir * 512 + j0 + w * 4 + lane;
      if (fast)  // plain store -> write-through L1 -> local L2: fast visibility
        __hip_atomic_store(dst, hnew, __ATOMIC_RELAXED,
                           __HIP_MEMORY_SCOPE_WORKGROUP);
      // agent store -> device coherence point: guarantees the fallback path
      __hip_atomic_store(dst, hnew, __ATOMIC_RELAXED,
                         __HIP_MEMORY_SCOPE_AGENT);
    }
  }
}

// ---------------------------------------------------------------------------
// classifier: hid = relu(W1 @ [hf;hb] + b1); logits = W2 @ hid + b2; softmax
// ---------------------------------------------------------------------------
__global__ __launch_bounds__(1024) void cls_kernel(
    const float* __restrict__ Hfin,  // Hbuf slot SEQ_L: [dir][512]
    const float* __restrict__ W1, const float* __restrict__ b1,
    const float* __restrict__ W2, const float* __restrict__ b2,
    float* __restrict__ out) {
  __shared__ float hcat[1024];
  __shared__ float hid[512];
  __shared__ float logits[NCLS];
  const int tid = threadIdx.x;
  hcat[tid] = Hfin[tid];
  __syncthreads();

  const int lane = tid & 63, widx = tid >> 6;
  for (int rr = 0; rr < 32; ++rr) {
    int row = widx * 32 + rr;
    const float4* wrow = reinterpret_cast<const float4*>(W1 + (size_t)row * 1024);
    float acc = 0.0f;
#pragma unroll
    for (int c = 0; c < 4; ++c) {
      int k = c * 256 + lane * 4;
      float4 v = wrow[c * 64 + lane];
      acc += v.x * hcat[k] + v.y * hcat[k + 1] + v.z * hcat[k + 2] +
             v.w * hcat[k + 3];
    }
#pragma unroll
    for (int mask = 32; mask >= 1; mask >>= 1) acc += __shfl_xor(acc, mask, 64);
    if (lane == 0) hid[row] = fmaxf(acc + b1[row], 0.0f);
  }
  __syncthreads();

  if (tid < NCLS) {
    const float4* wrow = reinterpret_cast<const float4*>(W2 + (size_t)tid * 512);
    float acc = 0.0f;
    for (int q = 0; q < 128; ++q) {
      float4 v = wrow[q];
      int k = q * 4;
      acc += v.x * hid[k] + v.y * hid[k + 1] + v.z * hid[k + 2] +
             v.w * hid[k + 3];
    }
    logits[tid] = acc + b2[tid];
  }
  __syncthreads();

  if (tid == 0) {
    float m = -1e30f;
    for (int i = 0; i < NCLS; ++i) m = fmaxf(m, logits[i]);
    float s = 0.0f;
    float e[NCLS];
    for (int i = 0; i < NCLS; ++i) { e[i] = __expf(logits[i] - m); s += e[i]; }
    float inv = 1.0f / s;
    for (int i = 0; i < NCLS; ++i) out[i] = e[i] * inv;
  }
}

// ---------------------------------------------------------------------------
extern "C" void kernel_launch(void* const* d_in, const int* in_sizes, int n_in,
                              void* d_out, int out_size, void* d_ws,
                              size_t ws_size, hipStream_t stream) {
  (void)in_sizes; (void)n_in; (void)out_size; (void)ws_size;
  const int*   seq   = (const int*)d_in[0];
  const float* emb   = (const float*)d_in[1];
  const float* Wih_f = (const float*)d_in[2];
  const float* Whh_f = (const float*)d_in[3];
  const float* bih_f = (const float*)d_in[4];
  const float* bhh_f = (const float*)d_in[5];
  const float* Wih_b = (const float*)d_in[6];
  const float* Whh_b = (const float*)d_in[7];
  const float* bih_b = (const float*)d_in[8];
  const float* bhh_b = (const float*)d_in[9];
  const float* W1    = (const float*)d_in[10];
  const float* b1    = (const float*)d_in[11];
  const float* W2    = (const float*)d_in[12];
  const float* b2    = (const float*)d_in[13];
  float* out = (float*)d_out;

  float* gi_f = (float*)d_ws;                   // 2048*1536 f32 (12.6 MB)
  float* gi_b = gi_f + (size_t)SEQ_L * 1536;    // 12.6 MB
  float* Hbuf = gi_b + (size_t)SEQ_L * 1536;    // 2049*1024 f32 (8.4 MB)
  unsigned* census = (unsigned*)(Hbuf + (size_t)2049 * 1024);  // 256 dwords

  hipLaunchKernelGGL(init_kernel, dim3(513), dim3(256), 0, stream,
                     (uint4*)Hbuf);
  hipLaunchKernelGGL(gi_kernel, dim3(SEQ_L / 8, 2), dim3(256), 0, stream,
                     seq, emb, Wih_f, bih_f, bhh_f, Wih_b, bih_b, bhh_b,
                     gi_f, gi_b);
  hipLaunchKernelGGL(rnn_kernel, dim3(NWG), dim3(512), 0, stream,
                     Whh_f, bhh_f, Whh_b, bhh_b, gi_f, gi_b, Hbuf, census);
  hipLaunchKernelGGL(cls_kernel, dim3(1), dim3(1024), 0, stream,
                     Hbuf + (size_t)SEQ_L * 1024, W1, b1, W2, b2, out);
}